// Round 6
// baseline (61.338 us; speedup 1.0000x reference)
//
#include <hip/hip_runtime.h>
#include <math.h>

#define S 76
#define A 3
#define CH 85            // 5 + 80
#define NCLS 80
#define MAXGT 150
#define CPB (S * S * A)              // 17328 cells per batch
#define FPB (CPB * CH)               // 1472880 floats per batch
#define BATCH 16
#define TOTF4 ((BATCH * FPB) / 4)    // 5,891,520 float4s total
#define BLK 256
#define ROUNDS 8
#define DEPTH 3                      // software-pipeline depth
#define STREAM_BLOCKS ((TOTF4 + BLK * ROUNDS - 1) / (BLK * ROUNDS))   // 2877
#define ATILE 128
#define AGX ((CPB + ATILE - 1) / ATILE)                               // 136
#define GEO_BLOCKS (AGX * BATCH)                                      // 2176
#define TOT_BLOCKS (STREAM_BLOCKS + GEO_BLOCKS)                       // 5053

__device__ __forceinline__ float frcp(float x) { return __builtin_amdgcn_rcpf(x); }
__device__ __forceinline__ float sigmoidf_(float x) { return frcp(1.f + __expf(-x)); }
// bce_with_logits(x,y) = ln(1+e^x) - x*y   (safe for |x| < ~80)
__device__ __forceinline__ float bcef(float x, float y) {
    const float t  = __builtin_amdgcn_exp2f(x * 1.44269504f);
    const float lg = __builtin_amdgcn_logf(1.f + t);            // log2(1+e^x)
    return __builtin_fmaf(0.69314718f, lg, -x * y);
}

// ---------------- fused kernel: block-role specialization ----------------
__global__ __launch_bounds__(BLK) void yolo_fused_kernel(
    const float* __restrict__ conv, const float* __restrict__ label,
    const float* __restrict__ bboxes, float* __restrict__ partA /*geo*/,
    float* __restrict__ partB /*stream*/)
{
    const unsigned bid = blockIdx.x;
    const int tid = threadIdx.x;
    // Bresenham role interleave: geo blocks evenly mixed among stream blocks.
    const unsigned geo_before = (unsigned)(((unsigned long long)bid * GEO_BLOCKS) / TOT_BLOCKS);
    const unsigned geo_after  = (unsigned)(((unsigned long long)(bid + 1) * GEO_BLOCKS) / TOT_BLOCKS);

    if (geo_after == geo_before) {
        // ================= STREAM role: prob_loss =================
        const unsigned sidx = bid - geo_before;
        const int base = (int)sidx * (BLK * ROUNDS);
        const float4* __restrict__ cv4 = (const float4*)conv;
        const float4* __restrict__ lb4 = (const float4*)label;

        float p_sum = 0.f;

        if (sidx + 1 < STREAM_BLOCKS) {
            // ---- fast path: block fully in range, depth-3 pipeline, no clamps ----
            float4 c_s[DEPTH], l_s[DEPTH];
            float  rs_s[DEPTH];
            unsigned r0_s[DEPTH];
            #pragma unroll
            for (int s = 0; s < DEPTH; ++s) {
                const int u = base + s * BLK + tid;
                c_s[s] = cv4[(size_t)u];
                l_s[s] = lb4[(size_t)u];
                const unsigned e0 = 4u * (unsigned)u;
                const unsigned c0 = e0 / 85u;
                r0_s[s] = e0 - 85u * c0;
                rs_s[s] = label[(size_t)c0 * CH + 4];
            }
            #pragma unroll
            for (int r = 0; r < ROUNDS; ++r) {
                const int sg = r % DEPTH;                  // compile-time
                const float4 cc = c_s[sg];
                const float4 lc = l_s[sg];
                const float rspc = rs_s[sg];
                const unsigned r0c = r0_s[sg];
                if (r + DEPTH < ROUNDS) {                  // refill stage (compile-time)
                    const int u = base + (r + DEPTH) * BLK + tid;
                    c_s[sg] = cv4[(size_t)u];
                    l_s[sg] = lb4[(size_t)u];
                    const unsigned e0 = 4u * (unsigned)u;
                    const unsigned c0 = e0 / 85u;
                    r0_s[sg] = e0 - 85u * c0;
                    rs_s[sg] = label[(size_t)c0 * CH + 4];
                }
                const float cx[4] = {cc.x, cc.y, cc.z, cc.w};
                const float lx[4] = {lc.x, lc.y, lc.z, lc.w};
                float s = 0.f;
                #pragma unroll
                for (int k = 0; k < 4; ++k) {
                    const unsigned rr = r0c + k;           // [0,87]
                    const float bv = bcef(cx[k], lx[k]);
                    s += ((rr - 5u) < 80u) ? bv : 0.f;     // channels 5..84 only
                }
                p_sum = __builtin_fmaf(rspc, s, p_sum);
            }
        } else {
            // ---- tail path: clamped (only the last stream block) ----
            for (int r = 0; r < ROUNDS; ++r) {
                const int u = base + r * BLK + tid;
                if (u >= TOTF4) break;
                const float4 cc = cv4[(size_t)u];
                const float4 lc = lb4[(size_t)u];
                const unsigned e0 = 4u * (unsigned)u;
                const unsigned c0 = e0 / 85u;
                const unsigned r0c = e0 - 85u * c0;
                const float rspc = label[(size_t)c0 * CH + 4];
                const float cx[4] = {cc.x, cc.y, cc.z, cc.w};
                const float lx[4] = {lc.x, lc.y, lc.z, lc.w};
                float s = 0.f;
                #pragma unroll
                for (int k = 0; k < 4; ++k) {
                    const unsigned rr = r0c + k;
                    const float bv = bcef(cx[k], lx[k]);
                    s += ((rr - 5u) < 80u) ? bv : 0.f;
                }
                p_sum = __builtin_fmaf(rspc, s, p_sum);
            }
        }

        for (int off = 32; off > 0; off >>= 1) p_sum += __shfl_down(p_sum, off, 64);
        __shared__ float sredp[BLK / 64];
        const int lane = tid & 63, wv = tid >> 6;
        if (lane == 0) sredp[wv] = p_sum;
        __syncthreads();
        if (tid == 0) {
            float P = 0.f;
            #pragma unroll
            for (int w = 0; w < BLK / 64; ++w) P += sredp[w];
            partB[sidx] = P;
        }
    } else {
        // ================= GEO role: giou_loss + conf_loss =================
        const unsigned gidx = geo_before;
        const int b    = gidx / AGX;
        const int tile = gidx - b * AGX;

        __shared__ float4 s_box[MAXGT];   // 3*x1, y1, 3*x2, y2
        __shared__ float  s_ba[MAXGT];

        const int ci = tid >> 1;
        const int pr = tid & 1;
        const int t = tile * ATILE + ci;
        const bool valid = (t < CPB);
        const int tc = valid ? t : (CPB - 1);

        const size_t boff = (size_t)b * FPB;
        const float* cv = conv  + boff + (size_t)tc * CH;
        const float* lb = label + boff + (size_t)tc * CH;

        if (tid < MAXGT) {
            const float4 bx = *(const float4*)(bboxes + (size_t)b * (MAXGT * 4) + tid * 4);
            const float hw = bx.z * 0.5f, hh = bx.w * 0.5f;
            s_box[tid] = make_float4(3.f * (bx.x - hw), bx.y - hh, 3.f * (bx.x + hw), bx.y + hh);
            s_ba[tid]  = bx.z * bx.w;
        }
        const float dx = cv[0], dy = cv[1], dw = cv[2], dh = cv[3], rc = cv[4];
        const float lx = lb[0], ly = lb[1], lw = lb[2], lh = lb[3], resp = lb[4];
        __syncthreads();

        const int i   = tc / (S * A);
        const int rem = tc - i * (S * A);
        const int j   = rem / A;
        const int a   = rem - j * A;
        const float aw = (a == 0) ? 12.f : ((a == 1) ? 19.f : 40.f);
        const float ah = (a == 0) ? 16.f : ((a == 1) ? 36.f : 28.f);

        const float px = (sigmoidf_(dx) * 1.2f - 0.1f + (float)j) * 8.f;
        const float py = (sigmoidf_(dy) * 1.2f - 0.1f + (float)i) * 8.f;
        const float pw = __expf(dw) * aw;
        const float ph = __expf(dh) * ah;
        const float pconf = sigmoidf_(rc);

        const float px1 = px - pw * 0.5f, py1 = py - ph * 0.5f;
        const float px2 = px + pw * 0.5f, py2 = py + ph * 0.5f;
        const float areap = pw * ph;

        const float px1_3 = 3.f * px1, px2_3 = 3.f * px2;
        float maxv = -1e30f;
        #pragma unroll 5
        for (int k = pr; k < MAXGT; k += 2) {
            const float4 bx = s_box[k];
            const float ba  = s_ba[k];
            const float kiw3 = fmaxf(fminf(px2_3, bx.z) - fmaxf(px1_3, bx.x), 0.f);
            const float kih  = fmaxf(fminf(py2, bx.w) - fmaxf(py1, bx.y), 0.f);
            maxv = fmaxf(maxv, __builtin_fmaf(kiw3, kih, -ba));
        }
        maxv = fmaxf(maxv, __shfl_xor(maxv, 1, 64));

        float g_sum = 0.f, c_sum = 0.f;
        if (pr == 0 && valid) {
            const float lx1 = lx - lw * 0.5f, ly1 = ly - lh * 0.5f;
            const float lx2 = lx + lw * 0.5f, ly2 = ly + lh * 0.5f;
            const float areal = lw * lh;
            const float iw = fmaxf(fminf(px2, lx2) - fmaxf(px1, lx1), 0.f);
            const float ih = fmaxf(fminf(py2, ly2) - fmaxf(py1, ly1), 0.f);
            const float inter = iw * ih;
            const float uni = areap + areal - inter;
            const float iou = inter * frcp(uni);
            const float ew = fmaxf(fmaxf(px2, lx2) - fminf(px1, lx1), 0.f);
            const float eh = fmaxf(fmaxf(py2, ly2) - fminf(py1, ly1), 0.f);
            const float enc = ew * eh;
            const float giou = iou - (enc - uni) * frcp(enc);
            g_sum = resp * (2.f - areal * (1.f / (608.f * 608.f))) * (1.f - giou);

            const float bgd = (1.f - resp) * ((maxv < areap) ? 1.f : 0.f);
            const float focal = (resp - pconf) * (resp - pconf);
            c_sum = focal * (resp + bgd) * bcef(rc, resp);
        }

        for (int off = 32; off > 0; off >>= 1) {
            g_sum += __shfl_down(g_sum, off, 64);
            c_sum += __shfl_down(c_sum, off, 64);
        }
        __shared__ float sred[2][BLK / 64];
        const int lane = tid & 63, wv = tid >> 6;
        if (lane == 0) { sred[0][wv] = g_sum; sred[1][wv] = c_sum; }
        __syncthreads();
        if (tid == 0) {
            float G = 0.f, C = 0.f;
            #pragma unroll
            for (int w = 0; w < BLK / 64; ++w) { G += sred[0][w]; C += sred[1][w]; }
            partA[gidx * 2 + 0] = G;
            partA[gidx * 2 + 1] = C;
        }
    }
}

// ---------------- final deterministic reduce ----------------
__global__ __launch_bounds__(256) void final_reduce(
    const float* __restrict__ partA, const float* __restrict__ partB,
    float* __restrict__ out, int nA, int nB, float invB)
{
    const int tid = threadIdx.x;
    float g = 0.f, c = 0.f, p = 0.f;
    for (int k = tid; k < nA; k += 256) { g += partA[2 * k]; c += partA[2 * k + 1]; }
    for (int k = tid; k < nB; k += 256) p += partB[k];
    for (int off = 32; off > 0; off >>= 1) {
        g += __shfl_down(g, off, 64);
        c += __shfl_down(c, off, 64);
        p += __shfl_down(p, off, 64);
    }
    __shared__ float sred[3][4];
    const int lane = tid & 63, wv = tid >> 6;
    if (lane == 0) { sred[0][wv] = g; sred[1][wv] = c; sred[2][wv] = p; }
    __syncthreads();
    if (tid == 0) {
        float G = 0.f, C = 0.f, P = 0.f;
        #pragma unroll
        for (int w = 0; w < 4; ++w) { G += sred[0][w]; C += sred[1][w]; P += sred[2][w]; }
        out[0] = G * invB;
        out[1] = C * invB;
        out[2] = P * invB;
    }
}

extern "C" void kernel_launch(void* const* d_in, const int* in_sizes, int n_in,
                              void* d_out, int out_size, void* d_ws, size_t ws_size,
                              hipStream_t stream) {
    const float* conv   = (const float*)d_in[0];
    const float* label  = (const float*)d_in[1];
    const float* bboxes = (const float*)d_in[2];
    float* out  = (float*)d_out;
    float* wsf  = (float*)d_ws;
    float* partA = wsf;                 // GEO_BLOCKS*2 = 4352 floats
    float* partB = wsf + 8192;          // STREAM_BLOCKS = 2877 floats

    yolo_fused_kernel<<<TOT_BLOCKS, BLK, 0, stream>>>(conv, label, bboxes, partA, partB);
    final_reduce<<<1, 256, 0, stream>>>(partA, partB, out, GEO_BLOCKS, STREAM_BLOCKS,
                                        1.f / (float)BATCH);
}

// Round 7
// 59.379 us; speedup vs baseline: 1.0330x; 1.0330x over previous
//
#include <hip/hip_runtime.h>
#include <math.h>

#define S 76
#define A 3
#define CH 85            // 5 + 80
#define NCLS 80
#define MAXGT 150
#define CPB (S * S * A)              // 17328 cells per batch
#define FPB (CPB * CH)               // 1472880 floats per batch
#define BATCH 16
#define TOTF4 ((BATCH * FPB) / 4)    // 5,891,520 float4s total
#define BLK 256
#define ROUNDS 8
#define STREAM_BLOCKS ((TOTF4 + BLK * ROUNDS - 1) / (BLK * ROUNDS))   // 2877
#define ATILE 128
#define AGX ((CPB + ATILE - 1) / ATILE)                               // 136
#define GEO_BLOCKS (AGX * BATCH)                                      // 2176
#define TOT_BLOCKS (STREAM_BLOCKS + GEO_BLOCKS)                       // 5053

__device__ __forceinline__ float frcp(float x) { return __builtin_amdgcn_rcpf(x); }
__device__ __forceinline__ float sigmoidf_(float x) { return frcp(1.f + __expf(-x)); }
// bce_with_logits(x,y) = ln(1+e^x) - x*y   (safe for |x| < ~80)
__device__ __forceinline__ float bcef(float x, float y) {
    const float t  = __builtin_amdgcn_exp2f(x * 1.44269504f);
    const float lg = __builtin_amdgcn_logf(1.f + t);            // log2(1+e^x)
    return __builtin_fmaf(0.69314718f, lg, -x * y);
}

// ---------------- fused kernel: block-role specialization ----------------
__global__ __launch_bounds__(BLK, 1) void yolo_fused_kernel(
    const float* __restrict__ conv, const float* __restrict__ label,
    const float* __restrict__ bboxes, float* __restrict__ partA /*geo*/,
    float* __restrict__ partB /*stream*/)
{
    const unsigned bid = blockIdx.x;
    const int tid = threadIdx.x;
    // Bresenham role interleave: geo blocks evenly mixed among stream blocks.
    const unsigned geo_before = (unsigned)(((unsigned long long)bid * GEO_BLOCKS) / TOT_BLOCKS);
    const unsigned geo_after  = (unsigned)(((unsigned long long)(bid + 1) * GEO_BLOCKS) / TOT_BLOCKS);

    if (geo_after == geo_before) {
        // ================= STREAM role: prob_loss =================
        const unsigned sidx = bid - geo_before;
        const int base = (int)sidx * (BLK * ROUNDS);
        const float4* __restrict__ cv4 = (const float4*)conv;
        const float4* __restrict__ lb4 = (const float4*)label;

        float p_sum = 0.f;

        if (sidx + 1 < STREAM_BLOCKS) {
            // ---- fast path: issue ALL loads first, fence, then compute.
            // sched_barrier(0) pins the 24 loads before the fence -> backend
            // emits counted vmcnt waits (deep pipeline, latency amortized 8x).
            float4 c_s[ROUNDS], l_s[ROUNDS];
            float  rs_s[ROUNDS];
            unsigned r0_s[ROUNDS];
            #pragma unroll
            for (int r = 0; r < ROUNDS; ++r) {
                const int u = base + r * BLK + tid;
                c_s[r] = cv4[(size_t)u];
                l_s[r] = lb4[(size_t)u];
                const unsigned e0 = 4u * (unsigned)u;
                const unsigned c0 = e0 / 85u;
                r0_s[r] = e0 - 85u * c0;
                rs_s[r] = label[(size_t)c0 * CH + 4];
            }
            __builtin_amdgcn_sched_barrier(0);
            #pragma unroll
            for (int r = 0; r < ROUNDS; ++r) {
                const float4 cc = c_s[r];
                const float4 lc = l_s[r];
                const float rspc = rs_s[r];
                const unsigned r0c = r0_s[r];
                const float cx[4] = {cc.x, cc.y, cc.z, cc.w};
                const float lx[4] = {lc.x, lc.y, lc.z, lc.w};
                float s = 0.f;
                #pragma unroll
                for (int k = 0; k < 4; ++k) {
                    const unsigned rr = r0c + k;           // [0,87]
                    const float bv = bcef(cx[k], lx[k]);
                    s += ((rr - 5u) < 80u) ? bv : 0.f;     // channels 5..84 only
                }
                p_sum = __builtin_fmaf(rspc, s, p_sum);
            }
        } else {
            // ---- tail path: clamped (only the last stream block) ----
            for (int r = 0; r < ROUNDS; ++r) {
                const int u = base + r * BLK + tid;
                if (u >= TOTF4) break;
                const float4 cc = cv4[(size_t)u];
                const float4 lc = lb4[(size_t)u];
                const unsigned e0 = 4u * (unsigned)u;
                const unsigned c0 = e0 / 85u;
                const unsigned r0c = e0 - 85u * c0;
                const float rspc = label[(size_t)c0 * CH + 4];
                const float cx[4] = {cc.x, cc.y, cc.z, cc.w};
                const float lx[4] = {lc.x, lc.y, lc.z, lc.w};
                float s = 0.f;
                #pragma unroll
                for (int k = 0; k < 4; ++k) {
                    const unsigned rr = r0c + k;
                    const float bv = bcef(cx[k], lx[k]);
                    s += ((rr - 5u) < 80u) ? bv : 0.f;
                }
                p_sum = __builtin_fmaf(rspc, s, p_sum);
            }
        }

        for (int off = 32; off > 0; off >>= 1) p_sum += __shfl_down(p_sum, off, 64);
        __shared__ float sredp[BLK / 64];
        const int lane = tid & 63, wv = tid >> 6;
        if (lane == 0) sredp[wv] = p_sum;
        __syncthreads();
        if (tid == 0) {
            float P = 0.f;
            #pragma unroll
            for (int w = 0; w < BLK / 64; ++w) P += sredp[w];
            partB[sidx] = P;
        }
    } else {
        // ================= GEO role: giou_loss + conf_loss =================
        const unsigned gidx = geo_before;
        const int b    = gidx / AGX;
        const int tile = gidx - b * AGX;

        __shared__ float4 s_box[MAXGT];   // 3*x1, y1, 3*x2, y2
        __shared__ float  s_ba[MAXGT];

        const int ci = tid >> 1;
        const int pr = tid & 1;
        const int t = tile * ATILE + ci;
        const bool valid = (t < CPB);
        const int tc = valid ? t : (CPB - 1);

        const size_t boff = (size_t)b * FPB;
        const float* cv = conv  + boff + (size_t)tc * CH;
        const float* lb = label + boff + (size_t)tc * CH;

        if (tid < MAXGT) {
            const float4 bx = *(const float4*)(bboxes + (size_t)b * (MAXGT * 4) + tid * 4);
            const float hw = bx.z * 0.5f, hh = bx.w * 0.5f;
            s_box[tid] = make_float4(3.f * (bx.x - hw), bx.y - hh, 3.f * (bx.x + hw), bx.y + hh);
            s_ba[tid]  = bx.z * bx.w;
        }
        const float dx = cv[0], dy = cv[1], dw = cv[2], dh = cv[3], rc = cv[4];
        const float lx = lb[0], ly = lb[1], lw = lb[2], lh = lb[3], resp = lb[4];
        __syncthreads();

        const int i   = tc / (S * A);
        const int rem = tc - i * (S * A);
        const int j   = rem / A;
        const int a   = rem - j * A;
        const float aw = (a == 0) ? 12.f : ((a == 1) ? 19.f : 40.f);
        const float ah = (a == 0) ? 16.f : ((a == 1) ? 36.f : 28.f);

        const float px = (sigmoidf_(dx) * 1.2f - 0.1f + (float)j) * 8.f;
        const float py = (sigmoidf_(dy) * 1.2f - 0.1f + (float)i) * 8.f;
        const float pw = __expf(dw) * aw;
        const float ph = __expf(dh) * ah;
        const float pconf = sigmoidf_(rc);

        const float px1 = px - pw * 0.5f, py1 = py - ph * 0.5f;
        const float px2 = px + pw * 0.5f, py2 = py + ph * 0.5f;
        const float areap = pw * ph;

        const float px1_3 = 3.f * px1, px2_3 = 3.f * px2;
        float maxv = -1e30f;
        #pragma unroll 5
        for (int k = pr; k < MAXGT; k += 2) {
            const float4 bx = s_box[k];
            const float ba  = s_ba[k];
            const float kiw3 = fmaxf(fminf(px2_3, bx.z) - fmaxf(px1_3, bx.x), 0.f);
            const float kih  = fmaxf(fminf(py2, bx.w) - fmaxf(py1, bx.y), 0.f);
            maxv = fmaxf(maxv, __builtin_fmaf(kiw3, kih, -ba));
        }
        maxv = fmaxf(maxv, __shfl_xor(maxv, 1, 64));

        float g_sum = 0.f, c_sum = 0.f;
        if (pr == 0 && valid) {
            const float lx1 = lx - lw * 0.5f, ly1 = ly - lh * 0.5f;
            const float lx2 = lx + lw * 0.5f, ly2 = ly + lh * 0.5f;
            const float areal = lw * lh;
            const float iw = fmaxf(fminf(px2, lx2) - fmaxf(px1, lx1), 0.f);
            const float ih = fmaxf(fminf(py2, ly2) - fmaxf(py1, ly1), 0.f);
            const float inter = iw * ih;
            const float uni = areap + areal - inter;
            const float iou = inter * frcp(uni);
            const float ew = fmaxf(fmaxf(px2, lx2) - fminf(px1, lx1), 0.f);
            const float eh = fmaxf(fmaxf(py2, ly2) - fminf(py1, ly1), 0.f);
            const float enc = ew * eh;
            const float giou = iou - (enc - uni) * frcp(enc);
            g_sum = resp * (2.f - areal * (1.f / (608.f * 608.f))) * (1.f - giou);

            const float bgd = (1.f - resp) * ((maxv < areap) ? 1.f : 0.f);
            const float focal = (resp - pconf) * (resp - pconf);
            c_sum = focal * (resp + bgd) * bcef(rc, resp);
        }

        for (int off = 32; off > 0; off >>= 1) {
            g_sum += __shfl_down(g_sum, off, 64);
            c_sum += __shfl_down(c_sum, off, 64);
        }
        __shared__ float sred[2][BLK / 64];
        const int lane = tid & 63, wv = tid >> 6;
        if (lane == 0) { sred[0][wv] = g_sum; sred[1][wv] = c_sum; }
        __syncthreads();
        if (tid == 0) {
            float G = 0.f, C = 0.f;
            #pragma unroll
            for (int w = 0; w < BLK / 64; ++w) { G += sred[0][w]; C += sred[1][w]; }
            partA[gidx * 2 + 0] = G;
            partA[gidx * 2 + 1] = C;
        }
    }
}

// ---------------- final deterministic reduce ----------------
__global__ __launch_bounds__(256) void final_reduce(
    const float* __restrict__ partA, const float* __restrict__ partB,
    float* __restrict__ out, int nA, int nB, float invB)
{
    const int tid = threadIdx.x;
    float g = 0.f, c = 0.f, p = 0.f;
    for (int k = tid; k < nA; k += 256) { g += partA[2 * k]; c += partA[2 * k + 1]; }
    for (int k = tid; k < nB; k += 256) p += partB[k];
    for (int off = 32; off > 0; off >>= 1) {
        g += __shfl_down(g, off, 64);
        c += __shfl_down(c, off, 64);
        p += __shfl_down(p, off, 64);
    }
    __shared__ float sred[3][4];
    const int lane = tid & 63, wv = tid >> 6;
    if (lane == 0) { sred[0][wv] = g; sred[1][wv] = c; sred[2][wv] = p; }
    __syncthreads();
    if (tid == 0) {
        float G = 0.f, C = 0.f, P = 0.f;
        #pragma unroll
        for (int w = 0; w < 4; ++w) { G += sred[0][w]; C += sred[1][w]; P += sred[2][w]; }
        out[0] = G * invB;
        out[1] = C * invB;
        out[2] = P * invB;
    }
}

extern "C" void kernel_launch(void* const* d_in, const int* in_sizes, int n_in,
                              void* d_out, int out_size, void* d_ws, size_t ws_size,
                              hipStream_t stream) {
    const float* conv   = (const float*)d_in[0];
    const float* label  = (const float*)d_in[1];
    const float* bboxes = (const float*)d_in[2];
    float* out  = (float*)d_out;
    float* wsf  = (float*)d_ws;
    float* partA = wsf;                 // GEO_BLOCKS*2 = 4352 floats
    float* partB = wsf + 8192;          // STREAM_BLOCKS = 2877 floats

    yolo_fused_kernel<<<TOT_BLOCKS, BLK, 0, stream>>>(conv, label, bboxes, partA, partB);
    final_reduce<<<1, 256, 0, stream>>>(partA, partB, out, GEO_BLOCKS, STREAM_BLOCKS,
                                        1.f / (float)BATCH);
}